// Round 4
// baseline (1053.806 us; speedup 1.0000x reference)
//
#include <hip/hip_runtime.h>
#include <math.h>

#define C_CH 512
#define HW   1024
#define GROUPS 32
#define CPG  16
#define EPS  1e-5f
#define HEADS 8
#define HD   64
#define SCALE 0.125f   // 64^-0.5

// ---------------- GroupNorm: one block per (group, batch) ----------------
__global__ __launch_bounds__(256) void gn_kernel(
    const float* __restrict__ x, const float* __restrict__ gamma,
    const float* __restrict__ beta, float* __restrict__ xn) {
  const int g = blockIdx.x;   // 0..31
  const int b = blockIdx.y;   // 0..15
  const int t = threadIdx.x;  // 0..255
  const size_t base = ((size_t)b * C_CH + (size_t)g * CPG) * HW; // 16384 floats, contiguous
  const float4* __restrict__ xin4 = (const float4*)(x + base);

  float s = 0.f, ss = 0.f;
  float4 v[16];
#pragma unroll
  for (int i = 0; i < 16; ++i) {
    float4 a = xin4[t + i * 256];
    v[i] = a;
    s  += a.x + a.y + a.z + a.w;
    ss += a.x * a.x + a.y * a.y + a.z * a.z + a.w * a.w;
  }
#pragma unroll
  for (int m = 32; m >= 1; m >>= 1) {
    s  += __shfl_xor(s, m);
    ss += __shfl_xor(ss, m);
  }
  __shared__ float red[8];
  const int wave = t >> 6;
  if ((t & 63) == 0) { red[wave * 2] = s; red[wave * 2 + 1] = ss; }
  __syncthreads();
  s  = red[0] + red[2] + red[4] + red[6];
  ss = red[1] + red[3] + red[5] + red[7];
  const float mean = s * (1.f / 16384.f);
  const float var  = ss * (1.f / 16384.f) - mean * mean;
  const float inv  = rsqrtf(var + EPS);

  float4* __restrict__ xo4 = (float4*)(xn + base);
#pragma unroll
  for (int i = 0; i < 16; ++i) {
    const int f4 = t + i * 256;
    const int ch = f4 >> 8;                 // 256 float4 per channel
    const float gm = gamma[g * CPG + ch] * inv;
    const float bt = beta[g * CPG + ch];
    float4 a = v[i], o;
    o.x = (a.x - mean) * gm + bt;
    o.y = (a.y - mean) * gm + bt;
    o.z = (a.z - mean) * gm + bt;
    o.w = (a.w - mean) * gm + bt;
    xo4[f4] = o;
  }
}

// ---------------- fp32 GEMM: C[b] = A(MxK=512) * B[b](512x1024) + bias (+res) --------
// 64x64 tile, BK=16, 256 threads, 4x4 microtile.
__global__ __launch_bounds__(256) void gemm_kernel(
    const float* __restrict__ A, const float* __restrict__ B0,
    const float* __restrict__ bias, const float* __restrict__ R0,
    float* __restrict__ C0, int M) {
  const int n0 = blockIdx.x * 64;
  const int m0 = blockIdx.y * 64;
  const int b  = blockIdx.z;
  const float* __restrict__ B = B0 + (size_t)b * C_CH * HW;
  float* __restrict__ Cp = C0 + (size_t)b * M * HW;
  const float* __restrict__ Rp = R0 ? (R0 + (size_t)b * M * HW) : nullptr;

  __shared__ float As[16][68];  // [kk][row], padded
  __shared__ float Bs[16][64];  // [kk][col]

  const int t  = threadIdx.x;
  const int tx = t & 15, ty = t >> 4;
  const int arow = t >> 2, ac4 = t & 3;   // A loader: 1 float4/thread
  const int brow = t >> 4, bc4 = t & 15;  // B loader: 1 float4/thread

  float acc[4][4] = {};

  for (int k0 = 0; k0 < C_CH; k0 += 16) {
    const float4 a  = *(const float4*)(A + (size_t)(m0 + arow) * C_CH + k0 + ac4 * 4);
    const float4 bb = *(const float4*)(B + (size_t)(k0 + brow) * HW + n0 + bc4 * 4);
    __syncthreads();
    As[ac4 * 4 + 0][arow] = a.x;
    As[ac4 * 4 + 1][arow] = a.y;
    As[ac4 * 4 + 2][arow] = a.z;
    As[ac4 * 4 + 3][arow] = a.w;
    *(float4*)&Bs[brow][bc4 * 4] = bb;
    __syncthreads();
#pragma unroll
    for (int kk = 0; kk < 16; ++kk) {
      const float4 a4 = *(const float4*)&As[kk][ty * 4];
      const float4 b4 = *(const float4*)&Bs[kk][tx * 4];
      const float av[4] = {a4.x, a4.y, a4.z, a4.w};
      const float bv[4] = {b4.x, b4.y, b4.z, b4.w};
#pragma unroll
      for (int i = 0; i < 4; ++i)
#pragma unroll
        for (int j = 0; j < 4; ++j)
          acc[i][j] = fmaf(av[i], bv[j], acc[i][j]);
    }
  }

#pragma unroll
  for (int i = 0; i < 4; ++i) {
    const int row = m0 + ty * 4 + i;
    const float bi = bias[row];
    float4 o = make_float4(acc[i][0] + bi, acc[i][1] + bi, acc[i][2] + bi, acc[i][3] + bi);
    const size_t off = (size_t)row * HW + n0 + tx * 4;
    if (Rp) {
      const float4 r = *(const float4*)(Rp + off);
      o.x += r.x; o.y += r.y; o.z += r.z; o.w += r.w;
    }
    *(float4*)(Cp + off) = o;
  }
}

// ---------------- flash attention: block = (qtile, head, batch) ----------------
// q,k,v laid out in qkv buffer as [b][3*512 channels][1024]; head h owns channels h*64..h*64+63.
__global__ __launch_bounds__(256) void attn_kernel(
    const float* __restrict__ qkv, float* __restrict__ out) {
  const int qb = blockIdx.x;  // 0..15 query tile
  const int h  = blockIdx.y;  // 0..7
  const int b  = blockIdx.z;  // 0..15
  const int t  = threadIdx.x;
  const int tx = t & 15, ty = t >> 4;

  __shared__ float Qs[64 * 64];  // [d][n]
  __shared__ float Ks[64 * 64];  // [d][m]
  __shared__ float Vs[64 * 64];  // [m][d ^ (m&28)]  (XOR swizzle)
  __shared__ float Ps[64 * 64];  // [q][k] probabilities / transpose scratch

  const size_t bh = ((size_t)b * 3 * C_CH + (size_t)h * HD) * HW;
  const float* __restrict__ qp = qkv + bh;
  const float* __restrict__ kp = qkv + bh + (size_t)C_CH * HW;
  const float* __restrict__ vp = qkv + bh + (size_t)2 * C_CH * HW;
  const int n0 = qb * 64;

  // Q tile (pre-scaled)
#pragma unroll
  for (int li = 0; li < 16; ++li) {
    const int flat = li * 256 + t;
    const int d = flat >> 6, n = flat & 63;
    Qs[flat] = qp[(size_t)d * HW + n0 + n] * SCALE;
  }

  float m_run[4], l_run[4], acc[4][4] = {};
#pragma unroll
  for (int i = 0; i < 4; ++i) { m_run[i] = -INFINITY; l_run[i] = 0.f; }

  for (int mt = 0; mt < 16; ++mt) {
    const int mbase = mt * 64;
    __syncthreads();  // previous tile's PV reads done
#pragma unroll
    for (int li = 0; li < 16; ++li) {
      const int flat = li * 256 + t;
      const int d = flat >> 6, m = flat & 63;
      Ks[flat] = kp[(size_t)d * HW + mbase + m];
      Vs[m * 64 + (d ^ (m & 28))] = vp[(size_t)d * HW + mbase + m];
    }
    __syncthreads();

    // S = Q^T K  (s[i][j]: query 4ty+i, key 4tx+j)
    float s[4][4] = {};
#pragma unroll 8
    for (int d = 0; d < 64; ++d) {
      const float4 q4 = *(const float4*)&Qs[d * 64 + ty * 4];
      const float4 k4 = *(const float4*)&Ks[d * 64 + tx * 4];
      const float av[4] = {q4.x, q4.y, q4.z, q4.w};
      const float bv[4] = {k4.x, k4.y, k4.z, k4.w};
#pragma unroll
      for (int i = 0; i < 4; ++i)
#pragma unroll
        for (int j = 0; j < 4; ++j)
          s[i][j] = fmaf(av[i], bv[j], s[i][j]);
    }

    // online softmax (rows are queries; 16 threads per row share via shfl_xor)
#pragma unroll
    for (int i = 0; i < 4; ++i) {
      float tm = fmaxf(fmaxf(s[i][0], s[i][1]), fmaxf(s[i][2], s[i][3]));
#pragma unroll
      for (int m = 8; m >= 1; m >>= 1) tm = fmaxf(tm, __shfl_xor(tm, m));
      const float mn = fmaxf(m_run[i], tm);
      const float al = __expf(m_run[i] - mn);
      float rs = 0.f;
#pragma unroll
      for (int j = 0; j < 4; ++j) {
        const float p = __expf(s[i][j] - mn);
        s[i][j] = p;
        rs += p;
      }
#pragma unroll
      for (int m = 8; m >= 1; m >>= 1) rs += __shfl_xor(rs, m);
      l_run[i] = l_run[i] * al + rs;
      m_run[i] = mn;
#pragma unroll
      for (int j = 0; j < 4; ++j) acc[i][j] *= al;
#pragma unroll
      for (int j = 0; j < 4; ++j) Ps[(ty * 4 + i) * 64 + tx * 4 + j] = s[i][j];
    }
    __syncthreads();

    // PV: acc[i][j] += P[q][m] * V[d=4tx+j][m]
#pragma unroll 4
    for (int m = 0; m < 64; ++m) {
      const float4 v4 = *(const float4*)&Vs[m * 64 + ((tx * 4) ^ (m & 28))];
      const float vv[4] = {v4.x, v4.y, v4.z, v4.w};
#pragma unroll
      for (int i = 0; i < 4; ++i) {
        const float p = Ps[(ty * 4 + i) * 64 + m];
#pragma unroll
        for (int j = 0; j < 4; ++j)
          acc[i][j] = fmaf(p, vv[j], acc[i][j]);
      }
    }
  }

  // epilogue: normalize, transpose via LDS (full XOR swizzle), coalesced store
  __syncthreads();
#pragma unroll
  for (int i = 0; i < 4; ++i) {
    const float invl = 1.f / l_run[i];
    const int n = 4 * ty + i;
#pragma unroll
    for (int j = 0; j < 4; ++j) {
      const int d = 4 * tx + j;
      Ps[n * 64 + (d ^ (n & 31))] = acc[i][j] * invl;
    }
  }
  __syncthreads();
  float* __restrict__ op = out + ((size_t)b * C_CH + (size_t)h * HD) * HW + n0;
#pragma unroll
  for (int li = 0; li < 16; ++li) {
    const int flat = li * 256 + t;
    const int d = flat >> 6, n = flat & 63;
    op[(size_t)d * HW + n] = Ps[n * 64 + (d ^ (n & 31))];
  }
}

// ---------------- launch ----------------
extern "C" void kernel_launch(void* const* d_in, const int* in_sizes, int n_in,
                              void* d_out, int out_size, void* d_ws, size_t ws_size,
                              hipStream_t stream) {
  (void)in_sizes; (void)n_in; (void)out_size; (void)ws_size;
  const float* x     = (const float*)d_in[0];
  const float* gamma = (const float*)d_in[1];
  const float* beta  = (const float*)d_in[2];
  const float* w_qkv = (const float*)d_in[3];
  const float* b_qkv = (const float*)d_in[4];
  const float* w_out = (const float*)d_in[5];
  const float* b_out = (const float*)d_in[6];
  float* out = (float*)d_out;

  float* xn    = (float*)d_ws;                        // 16*512*1024 fp32 (32 MiB)
  float* qkv   = xn + (size_t)16 * C_CH * HW;         // 16*1536*1024 fp32 (96 MiB)
  float* attno = xn;                                  // reuse xn after QKV GEMM

  gn_kernel<<<dim3(GROUPS, 16), 256, 0, stream>>>(x, gamma, beta, xn);
  gemm_kernel<<<dim3(16, 24, 16), 256, 0, stream>>>(w_qkv, xn, b_qkv, nullptr, qkv, 3 * C_CH);
  attn_kernel<<<dim3(16, HEADS, 16), 256, 0, stream>>>(qkv, attno);
  gemm_kernel<<<dim3(16, 8, 16), 256, 0, stream>>>(w_out, attno, b_out, x, out, C_CH);
}

// Round 6
// 819.879 us; speedup vs baseline: 1.2853x; 1.2853x over previous
//
#include <hip/hip_runtime.h>
#include <math.h>

#define C_CH 512
#define HW   1024
#define GROUPS 32
#define CPG  16
#define EPS  1e-5f
#define HEADS 8
#define HD   64
#define SCALE 0.125f   // 64^-0.5

typedef short bf16x8 __attribute__((ext_vector_type(8)));
typedef float f32x4  __attribute__((ext_vector_type(4)));
typedef unsigned short us8 __attribute__((ext_vector_type(8)));
typedef unsigned short us4 __attribute__((ext_vector_type(4)));

__device__ inline unsigned short f2bf(float x) {   // RNE float->bf16 bits
  unsigned u = __float_as_uint(x);
  u += 0x7fffu + ((u >> 16) & 1u);
  return (unsigned short)(u >> 16);
}
__device__ inline float bf2f(unsigned short h) {
  return __uint_as_float(((unsigned)h) << 16);
}

// ---------- convert fp32 array -> bf16 hi/lo (split) ----------
__global__ __launch_bounds__(256) void wconv(const float* __restrict__ w,
    unsigned short* __restrict__ hi, unsigned short* __restrict__ lo, int n8) {
  const int i = blockIdx.x * 256 + threadIdx.x;
  if (i >= n8) return;
  const float4* w4 = (const float4*)w;
  const float4 a = w4[i * 2], b = w4[i * 2 + 1];
  const float v[8] = {a.x, a.y, a.z, a.w, b.x, b.y, b.z, b.w};
  us8 h, l;
#pragma unroll
  for (int j = 0; j < 8; ++j) {
    const unsigned short hb = f2bf(v[j]);
    h[j] = hb;
    l[j] = f2bf(v[j] - bf2f(hb));
  }
  *(us8*)(hi + (size_t)i * 8) = h;
  *(us8*)(lo + (size_t)i * 8) = l;
}

// ---------- GroupNorm -> transposed split-bf16 output [b][hw][C] ----------
__global__ __launch_bounds__(256) void gn_t_kernel(
    const float* __restrict__ x, const float* __restrict__ gamma,
    const float* __restrict__ beta, unsigned short* __restrict__ xnt_hi,
    unsigned short* __restrict__ xnt_lo) {
  const int g = blockIdx.x;   // 0..31
  const int b = blockIdx.y;   // 0..15
  const int t = threadIdx.x;  // 0..255
  const size_t base = ((size_t)b * C_CH + (size_t)g * CPG) * HW;
  const float4* __restrict__ xin4 = (const float4*)(x + base);

  float s = 0.f, ss = 0.f;
  float4 v[16];   // thread t holds channels i=0..15 at hw = 4t..4t+3
#pragma unroll
  for (int i = 0; i < 16; ++i) {
    float4 a = xin4[t + i * 256];
    v[i] = a;
    s  += a.x + a.y + a.z + a.w;
    ss += a.x * a.x + a.y * a.y + a.z * a.z + a.w * a.w;
  }
#pragma unroll
  for (int m = 32; m >= 1; m >>= 1) {
    s  += __shfl_xor(s, m);
    ss += __shfl_xor(ss, m);
  }
  __shared__ float red[8];
  const int wave = t >> 6;
  if ((t & 63) == 0) { red[wave * 2] = s; red[wave * 2 + 1] = ss; }
  __syncthreads();
  s  = red[0] + red[2] + red[4] + red[6];
  ss = red[1] + red[3] + red[5] + red[7];
  const float mean = s * (1.f / 16384.f);
  const float var  = ss * (1.f / 16384.f) - mean * mean;
  const float inv  = rsqrtf(var + EPS);

  float gms[16], bts[16];
#pragma unroll
  for (int i = 0; i < 16; ++i) {
    gms[i] = gamma[g * CPG + i] * inv;
    bts[i] = beta[g * CPG + i];
  }

#pragma unroll
  for (int c = 0; c < 4; ++c) {
    unsigned short hh[16], ll[16];
#pragma unroll
    for (int i = 0; i < 16; ++i) {
      const float xv = (c == 0) ? v[i].x : (c == 1) ? v[i].y : (c == 2) ? v[i].z : v[i].w;
      const float y = (xv - mean) * gms[i] + bts[i];
      const unsigned short hb = f2bf(y);
      hh[i] = hb;
      ll[i] = f2bf(y - bf2f(hb));
    }
    const size_t off = ((size_t)b * HW + 4 * t + c) * C_CH + g * CPG;
    us8 H0, H1, L0, L1;
#pragma unroll
    for (int j = 0; j < 8; ++j) { H0[j] = hh[j]; H1[j] = hh[j + 8]; L0[j] = ll[j]; L1[j] = ll[j + 8]; }
    *(us8*)(xnt_hi + off)     = H0;
    *(us8*)(xnt_hi + off + 8) = H1;
    *(us8*)(xnt_lo + off)     = L0;
    *(us8*)(xnt_lo + off + 8) = L1;
  }
}

// ---------- transpose+split-convert: fp32 [b][512][1024] -> bf16 hi/lo [b][1024][512] ----------
__global__ __launch_bounds__(256) void t_conv(const float* __restrict__ in,
    unsigned short* __restrict__ hi, unsigned short* __restrict__ lo) {
  const int c0 = blockIdx.x * 64;   // channel tile
  const int h0 = blockIdx.y * 64;   // hw tile
  const int b  = blockIdx.z;
  __shared__ float s[64][68];
  const int t = threadIdx.x;
  const float* ip = in + (size_t)b * C_CH * HW;
#pragma unroll
  for (int r = 0; r < 4; ++r) {
    const int f4 = r * 256 + t;
    const int rc = f4 >> 4, c4 = f4 & 15;
    const float4 a = *(const float4*)(ip + (size_t)(c0 + rc) * HW + h0 + c4 * 4);
    s[rc][c4 * 4 + 0] = a.x; s[rc][c4 * 4 + 1] = a.y;
    s[rc][c4 * 4 + 2] = a.z; s[rc][c4 * 4 + 3] = a.w;
  }
  __syncthreads();
  unsigned short* hp = hi + (size_t)b * HW * C_CH;
  unsigned short* lp = lo + (size_t)b * HW * C_CH;
#pragma unroll
  for (int r = 0; r < 4; ++r) {
    const int u = r * 256 + t;
    const int hw = u >> 4, c4 = u & 15;
    us4 H, L;
#pragma unroll
    for (int j = 0; j < 4; ++j) {
      const float xv = s[c4 * 4 + j][hw];
      const unsigned short hb = f2bf(xv);
      H[j] = hb;
      L[j] = f2bf(xv - bf2f(hb));
    }
    const size_t off = (size_t)(h0 + hw) * C_CH + c0 + c4 * 4;
    *(us4*)(hp + off) = H;
    *(us4*)(lp + off) = L;
  }
}

// ---------- split-bf16 MFMA GEMM: C[b] = A(M x 512) * B[b]^T (B stored [1024][512]) ----------
// BM=BN=128, BK=64, 256 threads = 4 waves (2x2), per-wave 64x64 via 4x4 frags of 16x16x32.
__global__ __launch_bounds__(256, 2) void gemm_bt_split(
    const unsigned short* __restrict__ Ah, const unsigned short* __restrict__ Al,
    const unsigned short* __restrict__ Bh0, const unsigned short* __restrict__ Bl0,
    const float* __restrict__ bias, const float* __restrict__ R0,
    float* __restrict__ C0, int M) {
  const int n0 = blockIdx.x * 128;
  const int m0 = blockIdx.y * 128;
  const int b  = blockIdx.z;
  const unsigned short* __restrict__ Bh = Bh0 + (size_t)b * HW * C_CH;
  const unsigned short* __restrict__ Bl = Bl0 + (size_t)b * HW * C_CH;
  float* __restrict__ Cp = C0 + (size_t)b * M * HW;
  const float* __restrict__ Rp = R0 ? (R0 + (size_t)b * M * HW) : nullptr;

  __shared__ unsigned short sAh[128 * 64], sAl[128 * 64], sBh[128 * 64], sBl[128 * 64];

  const int t  = threadIdx.x;
  const int l  = t & 63, w = t >> 6;
  const int wm = w >> 1, wn = w & 1;
  const int ln = l & 15, lg = l >> 4;

  f32x4 acc[4][4];
#pragma unroll
  for (int i = 0; i < 4; ++i)
#pragma unroll
    for (int j = 0; j < 4; ++j) acc[i][j] = (f32x4){0.f, 0.f, 0.f, 0.f};

  for (int k0 = 0; k0 < C_CH; k0 += 64) {
    __syncthreads();
    // stage 4 tiles of [128 rows][64 k] bf16, XOR-swizzled 16B chunks within row
#pragma unroll
    for (int rr = 0; rr < 4; ++rr) {
      const int flat = rr * 256 + t;            // 0..1023
      const int row = flat >> 3, ch = flat & 7; // 128 rows x 8 chunks(16B)
      const int dst = row * 64 + (ch ^ (row & 7)) * 8;
      const size_t asrc = (size_t)(m0 + row) * C_CH + k0 + ch * 8;
      const size_t bsrc = (size_t)(n0 + row) * C_CH + k0 + ch * 8;
      *(bf16x8*)&sAh[dst] = *(const bf16x8*)(Ah + asrc);
      *(bf16x8*)&sAl[dst] = *(const bf16x8*)(Al + asrc);
      *(bf16x8*)&sBh[dst] = *(const bf16x8*)(Bh + bsrc);
      *(bf16x8*)&sBl[dst] = *(const bf16x8*)(Bl + bsrc);
    }
    __syncthreads();
#pragma unroll
    for (int ks = 0; ks < 2; ++ks) {
      bf16x8 bhf[4], blf[4];
#pragma unroll
      for (int fn = 0; fn < 4; ++fn) {
        const int row = wn * 64 + fn * 16 + ln;
        const int off = row * 64 + ((ks * 4 + lg) ^ (row & 7)) * 8;
        bhf[fn] = *(const bf16x8*)&sBh[off];
        blf[fn] = *(const bf16x8*)&sBl[off];
      }
#pragma unroll
      for (int fm = 0; fm < 4; ++fm) {
        const int row = wm * 64 + fm * 16 + ln;
        const int off = row * 64 + ((ks * 4 + lg) ^ (row & 7)) * 8;
        const bf16x8 ahf = *(const bf16x8*)&sAh[off];
        const bf16x8 alf = *(const bf16x8*)&sAl[off];
#pragma unroll
        for (int fn = 0; fn < 4; ++fn) {
          acc[fm][fn] = __builtin_amdgcn_mfma_f32_16x16x32_bf16(ahf, bhf[fn], acc[fm][fn], 0, 0, 0);
          acc[fm][fn] = __builtin_amdgcn_mfma_f32_16x16x32_bf16(ahf, blf[fn], acc[fm][fn], 0, 0, 0);
          acc[fm][fn] = __builtin_amdgcn_mfma_f32_16x16x32_bf16(alf, bhf[fn], acc[fm][fn], 0, 0, 0);
        }
      }
    }
  }
  // epilogue: C/D map col=lane&15, row=(lane>>4)*4+r (m89-verified)
#pragma unroll
  for (int fm = 0; fm < 4; ++fm) {
#pragma unroll
    for (int r = 0; r < 4; ++r) {
      const int row = m0 + wm * 64 + fm * 16 + lg * 4 + r;
      const float bi = bias[row];
#pragma unroll
      for (int fn = 0; fn < 4; ++fn) {
        const int col = n0 + wn * 64 + fn * 16 + ln;
        const size_t off = (size_t)row * HW + col;
        float vo = acc[fm][fn][r] + bi;
        if (Rp) vo += Rp[off];
        Cp[off] = vo;
      }
    }
  }
}

// ---------------- flash attention (unchanged fp32 anchor) ----------------
__global__ __launch_bounds__(256) void attn_kernel(
    const float* __restrict__ qkv, float* __restrict__ out) {
  const int qb = blockIdx.x;
  const int h  = blockIdx.y;
  const int b  = blockIdx.z;
  const int t  = threadIdx.x;
  const int tx = t & 15, ty = t >> 4;

  __shared__ float Qs[64 * 64];
  __shared__ float Ks[64 * 64];
  __shared__ float Vs[64 * 64];
  __shared__ float Ps[64 * 64];

  const size_t bh = ((size_t)b * 3 * C_CH + (size_t)h * HD) * HW;
  const float* __restrict__ qp = qkv + bh;
  const float* __restrict__ kp = qkv + bh + (size_t)C_CH * HW;
  const float* __restrict__ vp = qkv + bh + (size_t)2 * C_CH * HW;
  const int n0 = qb * 64;

#pragma unroll
  for (int li = 0; li < 16; ++li) {
    const int flat = li * 256 + t;
    const int d = flat >> 6, n = flat & 63;
    Qs[flat] = qp[(size_t)d * HW + n0 + n] * SCALE;
  }

  float m_run[4], l_run[4], acc[4][4] = {};
#pragma unroll
  for (int i = 0; i < 4; ++i) { m_run[i] = -INFINITY; l_run[i] = 0.f; }

  for (int mt = 0; mt < 16; ++mt) {
    const int mbase = mt * 64;
    __syncthreads();
#pragma unroll
    for (int li = 0; li < 16; ++li) {
      const int flat = li * 256 + t;
      const int d = flat >> 6, m = flat & 63;
      Ks[flat] = kp[(size_t)d * HW + mbase + m];
      Vs[m * 64 + (d ^ (m & 28))] = vp[(size_t)d * HW + mbase + m];
    }
    __syncthreads();

    float s[4][4] = {};
#pragma unroll 8
    for (int d = 0; d < 64; ++d) {
      const float4 q4 = *(const float4*)&Qs[d * 64 + ty * 4];
      const float4 k4 = *(const float4*)&Ks[d * 64 + tx * 4];
      const float av[4] = {q4.x, q4.y, q4.z, q4.w};
      const float bv[4] = {k4.x, k4.y, k4.z, k4.w};
#pragma unroll
      for (int i = 0; i < 4; ++i)
#pragma unroll
        for (int j = 0; j < 4; ++j)
          s[i][j] = fmaf(av[i], bv[j], s[i][j]);
    }

#pragma unroll
    for (int i = 0; i < 4; ++i) {
      float tm = fmaxf(fmaxf(s[i][0], s[i][1]), fmaxf(s[i][2], s[i][3]));
#pragma unroll
      for (int m = 8; m >= 1; m >>= 1) tm = fmaxf(tm, __shfl_xor(tm, m));
      const float mn = fmaxf(m_run[i], tm);
      const float al = __expf(m_run[i] - mn);
      float rs = 0.f;
#pragma unroll
      for (int j = 0; j < 4; ++j) {
        const float p = __expf(s[i][j] - mn);
        s[i][j] = p;
        rs += p;
      }
#pragma unroll
      for (int m = 8; m >= 1; m >>= 1) rs += __shfl_xor(rs, m);
      l_run[i] = l_run[i] * al + rs;
      m_run[i] = mn;
#pragma unroll
      for (int j = 0; j < 4; ++j) acc[i][j] *= al;
#pragma unroll
      for (int j = 0; j < 4; ++j) Ps[(ty * 4 + i) * 64 + tx * 4 + j] = s[i][j];
    }
    __syncthreads();

#pragma unroll 4
    for (int m = 0; m < 64; ++m) {
      const float4 v4 = *(const float4*)&Vs[m * 64 + ((tx * 4) ^ (m & 28))];
      const float vv[4] = {v4.x, v4.y, v4.z, v4.w};
#pragma unroll
      for (int i = 0; i < 4; ++i) {
        const float p = Ps[(ty * 4 + i) * 64 + m];
#pragma unroll
        for (int j = 0; j < 4; ++j)
          acc[i][j] = fmaf(p, vv[j], acc[i][j]);
      }
    }
  }

  __syncthreads();
#pragma unroll
  for (int i = 0; i < 4; ++i) {
    const float invl = 1.f / l_run[i];
    const int n = 4 * ty + i;
#pragma unroll
    for (int j = 0; j < 4; ++j) {
      const int d = 4 * tx + j;
      Ps[n * 64 + (d ^ (n & 31))] = acc[i][j] * invl;
    }
  }
  __syncthreads();
  float* __restrict__ op = out + ((size_t)b * C_CH + (size_t)h * HD) * HW + n0;
#pragma unroll
  for (int li = 0; li < 16; ++li) {
    const int flat = li * 256 + t;
    const int d = flat >> 6, n = flat & 63;
    op[(size_t)d * HW + n] = Ps[n * 64 + (d ^ (n & 31))];
  }
}

// ---------------- launch ----------------
extern "C" void kernel_launch(void* const* d_in, const int* in_sizes, int n_in,
                              void* d_out, int out_size, void* d_ws, size_t ws_size,
                              hipStream_t stream) {
  (void)in_sizes; (void)n_in; (void)out_size; (void)ws_size;
  const float* x     = (const float*)d_in[0];
  const float* gamma = (const float*)d_in[1];
  const float* beta  = (const float*)d_in[2];
  const float* w_qkv = (const float*)d_in[3];
  const float* b_qkv = (const float*)d_in[4];
  const float* w_out = (const float*)d_in[5];
  const float* b_out = (const float*)d_in[6];
  float* out = (float*)d_out;

  // ws layout (128 MiB total, same footprint as the passing baseline):
  // [0,16M):  xnt_hi   -> later reused as attno fp32 [0,32M)
  // [16M,32M): xnt_lo
  // [32M,128M): qkv fp32 -> later reused: att_hi@32M, att_lo@48M, wo'@64M
  unsigned short* xnt_hi = (unsigned short*)d_ws;
  unsigned short* xnt_lo = xnt_hi + (size_t)16 * HW * C_CH;
  float* qkv   = (float*)((char*)d_ws + (size_t)32 * 1024 * 1024);
  float* attno = (float*)d_ws;
  unsigned short* att_hi = (unsigned short*)((char*)d_ws + (size_t)32 * 1024 * 1024);
  unsigned short* att_lo = att_hi + (size_t)16 * HW * C_CH;
  unsigned short* wo_hi  = (unsigned short*)((char*)d_ws + (size_t)64 * 1024 * 1024);
  unsigned short* wo_lo  = wo_hi + 512 * 512;
  // w_qkv hi/lo stashed in d_out (dead until final proj, which overwrites all of it)
  unsigned short* wq_hi = (unsigned short*)d_out;
  unsigned short* wq_lo = wq_hi + (size_t)1536 * 512;

  wconv<<<dim3(384), 256, 0, stream>>>(w_qkv, wq_hi, wq_lo, 98304);
  gn_t_kernel<<<dim3(GROUPS, 16), 256, 0, stream>>>(x, gamma, beta, xnt_hi, xnt_lo);
  gemm_bt_split<<<dim3(8, 12, 16), 256, 0, stream>>>(wq_hi, wq_lo, xnt_hi, xnt_lo,
                                                     b_qkv, nullptr, qkv, 3 * C_CH);
  attn_kernel<<<dim3(16, HEADS, 16), 256, 0, stream>>>(qkv, attno);
  t_conv<<<dim3(8, 16, 16), 256, 0, stream>>>(attno, att_hi, att_lo);
  wconv<<<dim3(128), 256, 0, stream>>>(w_out, wo_hi, wo_lo, 32768);
  gemm_bt_split<<<dim3(8, 4, 16), 256, 0, stream>>>(wo_hi, wo_lo, att_hi, att_lo,
                                                    b_out, x, out, C_CH);
}

// Round 7
// 697.085 us; speedup vs baseline: 1.5117x; 1.1762x over previous
//
#include <hip/hip_runtime.h>
#include <math.h>

#define C_CH 512
#define HW   1024
#define GROUPS 32
#define CPG  16
#define EPS  1e-5f
#define HEADS 8
#define HD   64
#define SCALE 0.125f   // 64^-0.5

typedef short bf16x8 __attribute__((ext_vector_type(8)));
typedef float f32x4  __attribute__((ext_vector_type(4)));
typedef unsigned short us8 __attribute__((ext_vector_type(8)));

__device__ inline unsigned short f2bf(float x) {   // RNE float->bf16 bits
  unsigned u = __float_as_uint(x);
  u += 0x7fffu + ((u >> 16) & 1u);
  return (unsigned short)(u >> 16);
}
__device__ inline float bf2f(unsigned short h) {
  return __uint_as_float(((unsigned)h) << 16);
}

// ---------- fp32 -> bf16 hi/lo split ----------
__global__ __launch_bounds__(256) void wconv(const float* __restrict__ w,
    unsigned short* __restrict__ hi, unsigned short* __restrict__ lo, int n8) {
  const int i = blockIdx.x * 256 + threadIdx.x;
  if (i >= n8) return;
  const float4* w4 = (const float4*)w;
  const float4 a = w4[i * 2], b = w4[i * 2 + 1];
  const float v[8] = {a.x, a.y, a.z, a.w, b.x, b.y, b.z, b.w};
  us8 h, l;
#pragma unroll
  for (int j = 0; j < 8; ++j) {
    const unsigned short hb = f2bf(v[j]);
    h[j] = hb;
    l[j] = f2bf(v[j] - bf2f(hb));
  }
  *(us8*)(hi + (size_t)i * 8) = h;
  *(us8*)(lo + (size_t)i * 8) = l;
}

// ---------- GroupNorm -> transposed split-bf16 [b][hw][512] ----------
__global__ __launch_bounds__(256) void gn_t_kernel(
    const float* __restrict__ x, const float* __restrict__ gamma,
    const float* __restrict__ beta, unsigned short* __restrict__ xnt_hi,
    unsigned short* __restrict__ xnt_lo) {
  const int g = blockIdx.x;
  const int b = blockIdx.y;
  const int t = threadIdx.x;
  const size_t base = ((size_t)b * C_CH + (size_t)g * CPG) * HW;
  const float4* __restrict__ xin4 = (const float4*)(x + base);

  float s = 0.f, ss = 0.f;
  float4 v[16];
#pragma unroll
  for (int i = 0; i < 16; ++i) {
    float4 a = xin4[t + i * 256];
    v[i] = a;
    s  += a.x + a.y + a.z + a.w;
    ss += a.x * a.x + a.y * a.y + a.z * a.z + a.w * a.w;
  }
#pragma unroll
  for (int m = 32; m >= 1; m >>= 1) {
    s  += __shfl_xor(s, m);
    ss += __shfl_xor(ss, m);
  }
  __shared__ float red[8];
  const int wave = t >> 6;
  if ((t & 63) == 0) { red[wave * 2] = s; red[wave * 2 + 1] = ss; }
  __syncthreads();
  s  = red[0] + red[2] + red[4] + red[6];
  ss = red[1] + red[3] + red[5] + red[7];
  const float mean = s * (1.f / 16384.f);
  const float var  = ss * (1.f / 16384.f) - mean * mean;
  const float inv  = rsqrtf(var + EPS);

  float gms[16], bts[16];
#pragma unroll
  for (int i = 0; i < 16; ++i) {
    gms[i] = gamma[g * CPG + i] * inv;
    bts[i] = beta[g * CPG + i];
  }
#pragma unroll
  for (int c = 0; c < 4; ++c) {
    unsigned short hh[16], ll[16];
#pragma unroll
    for (int i = 0; i < 16; ++i) {
      const float xv = (c == 0) ? v[i].x : (c == 1) ? v[i].y : (c == 2) ? v[i].z : v[i].w;
      const float y = (xv - mean) * gms[i] + bts[i];
      const unsigned short hb = f2bf(y);
      hh[i] = hb;
      ll[i] = f2bf(y - bf2f(hb));
    }
    const size_t off = ((size_t)b * HW + 4 * t + c) * C_CH + g * CPG;
    us8 H0, H1, L0, L1;
#pragma unroll
    for (int j = 0; j < 8; ++j) { H0[j] = hh[j]; H1[j] = hh[j + 8]; L0[j] = ll[j]; L1[j] = ll[j + 8]; }
    *(us8*)(xnt_hi + off)     = H0;
    *(us8*)(xnt_hi + off + 8) = H1;
    *(us8*)(xnt_lo + off)     = L0;
    *(us8*)(xnt_lo + off + 8) = L1;
  }
}

// ---------- QKV GEMM (swapped orientation): out[b][hw][1536ch] split-bf16 ----------
// A = xnt[b] [1024 hw][512], B = w_qkv [1536][512]; 128x128 tile, BK=64, 4 waves.
__global__ __launch_bounds__(256, 2) void gemm_xw(
    const unsigned short* __restrict__ Ah0, const unsigned short* __restrict__ Al0,
    const unsigned short* __restrict__ Bh, const unsigned short* __restrict__ Bl,
    const float* __restrict__ bias,
    unsigned short* __restrict__ qk_hi, unsigned short* __restrict__ qk_lo,
    unsigned short* __restrict__ vb_hi, unsigned short* __restrict__ vb_lo) {
  const int n0 = blockIdx.x * 128;   // out channel
  const int m0 = blockIdx.y * 128;   // hw
  const int bz = blockIdx.z;
  const unsigned short* __restrict__ Ah = Ah0 + (size_t)bz * HW * C_CH;
  const unsigned short* __restrict__ Al = Al0 + (size_t)bz * HW * C_CH;

  __shared__ unsigned short sAh[128 * 64], sAl[128 * 64], sBh[128 * 64], sBl[128 * 64];

  const int t  = threadIdx.x;
  const int l  = t & 63, w = t >> 6;
  const int wm = w >> 1, wn = w & 1;
  const int ln = l & 15, lg = l >> 4;

  f32x4 acc[4][4];
#pragma unroll
  for (int i = 0; i < 4; ++i)
#pragma unroll
    for (int j = 0; j < 4; ++j) acc[i][j] = (f32x4){0.f, 0.f, 0.f, 0.f};

  for (int k0 = 0; k0 < C_CH; k0 += 64) {
    __syncthreads();
#pragma unroll
    for (int rr = 0; rr < 4; ++rr) {
      const int flat = rr * 256 + t;
      const int row = flat >> 3, ch = flat & 7;
      const int dst = row * 64 + (ch ^ (row & 7)) * 8;
      const size_t asrc = (size_t)(m0 + row) * C_CH + k0 + ch * 8;
      const size_t bsrc = (size_t)(n0 + row) * C_CH + k0 + ch * 8;
      *(bf16x8*)&sAh[dst] = *(const bf16x8*)(Ah + asrc);
      *(bf16x8*)&sAl[dst] = *(const bf16x8*)(Al + asrc);
      *(bf16x8*)&sBh[dst] = *(const bf16x8*)(Bh + bsrc);
      *(bf16x8*)&sBl[dst] = *(const bf16x8*)(Bl + bsrc);
    }
    __syncthreads();
#pragma unroll
    for (int ks = 0; ks < 2; ++ks) {
      bf16x8 bhf[4], blf[4];
#pragma unroll
      for (int fn = 0; fn < 4; ++fn) {
        const int row = wn * 64 + fn * 16 + ln;
        const int off = row * 64 + ((ks * 4 + lg) ^ (row & 7)) * 8;
        bhf[fn] = *(const bf16x8*)&sBh[off];
        blf[fn] = *(const bf16x8*)&sBl[off];
      }
#pragma unroll
      for (int fm = 0; fm < 4; ++fm) {
        const int row = wm * 64 + fm * 16 + ln;
        const int off = row * 64 + ((ks * 4 + lg) ^ (row & 7)) * 8;
        const bf16x8 ahf = *(const bf16x8*)&sAh[off];
        const bf16x8 alf = *(const bf16x8*)&sAl[off];
#pragma unroll
        for (int fn = 0; fn < 4; ++fn) {
          acc[fm][fn] = __builtin_amdgcn_mfma_f32_16x16x32_bf16(ahf, bhf[fn], acc[fm][fn], 0, 0, 0);
          acc[fm][fn] = __builtin_amdgcn_mfma_f32_16x16x32_bf16(ahf, blf[fn], acc[fm][fn], 0, 0, 0);
          acc[fm][fn] = __builtin_amdgcn_mfma_f32_16x16x32_bf16(alf, bhf[fn], acc[fm][fn], 0, 0, 0);
        }
      }
    }
  }
  // epilogue: split-bf16; col<1024 -> qk (ld 1024), else -> vb (ld 512)
  const int isv = (n0 >= 1024);
  unsigned short* __restrict__ dh = isv ? vb_hi : qk_hi;
  unsigned short* __restrict__ dl = isv ? vb_lo : qk_lo;
  const int ldo = isv ? 512 : 1024;
  const int cb  = isv ? 1024 : 0;
#pragma unroll
  for (int fm = 0; fm < 4; ++fm) {
#pragma unroll
    for (int r = 0; r < 4; ++r) {
      const int row = m0 + wm * 64 + fm * 16 + lg * 4 + r;
      const size_t rb = ((size_t)bz * 1024 + row) * ldo;
#pragma unroll
      for (int fn = 0; fn < 4; ++fn) {
        const int col = n0 + wn * 64 + fn * 16 + ln;
        const float v = acc[fm][fn][r] + bias[col];
        const unsigned short hb = f2bf(v);
        const size_t o = rb + (col - cb);
        dh[o] = hb;
        dl[o] = f2bf(v - bf2f(hb));
      }
    }
  }
}

// ---------- V transpose: vb[b][hw][512] -> vt[b][512 (h*64+d)][1024 hw] ----------
// hi/lo packed in u32, element-XOR-swizzled LDS (conflict-free both sides).
__global__ __launch_bounds__(256) void vt_kernel(
    const unsigned short* __restrict__ vb_hi, const unsigned short* __restrict__ vb_lo,
    unsigned short* __restrict__ vt_hi, unsigned short* __restrict__ vt_lo) {
  const int hw0 = blockIdx.x * 64;
  const int h   = blockIdx.y;
  const int b   = blockIdx.z;
  const int t   = threadIdx.x;
  __shared__ unsigned T[64][64];
#pragma unroll
  for (int it = 0; it < 2; ++it) {
    const int flat = it * 256 + t;
    const int hwl = flat >> 3, c = flat & 7;
    const size_t src = ((size_t)b * 1024 + hw0 + hwl) * 512 + h * 64 + c * 8;
    const us8 H = *(const us8*)(vb_hi + src);
    const us8 L = *(const us8*)(vb_lo + src);
#pragma unroll
    for (int j = 0; j < 8; ++j) {
      const int d = c * 8 + j;
      T[hwl][d ^ (hwl & 31)] = (unsigned)H[j] | ((unsigned)L[j] << 16);
    }
  }
  __syncthreads();
#pragma unroll
  for (int it = 0; it < 2; ++it) {
    const int flat = it * 256 + t;
    const int dl = flat >> 3, hc = flat & 7;
    us8 H2, L2;
#pragma unroll
    for (int j = 0; j < 8; ++j) {
      const int hwl = hc * 8 + j;
      const unsigned u = T[hwl][dl ^ (hwl & 31)];
      H2[j] = (unsigned short)(u & 0xffffu);
      L2[j] = (unsigned short)(u >> 16);
    }
    const size_t dst = ((size_t)b * 512 + h * 64 + dl) * 1024 + hw0 + hc * 8;
    *(us8*)(vt_hi + dst) = H2;
    *(us8*)(vt_lo + dst) = L2;
  }
}

// ---------- MFMA flash attention ----------
// block: 64 queries x (h,b); 4 waves, wave-private 16 rows. No barriers in m-loop.
__global__ __launch_bounds__(256) void attn_mfma(
    const unsigned short* __restrict__ qk_hi, const unsigned short* __restrict__ qk_lo,
    const unsigned short* __restrict__ vt_hi, const unsigned short* __restrict__ vt_lo,
    unsigned short* __restrict__ att_hi, unsigned short* __restrict__ att_lo) {
  // XCD swizzle: co-locate the 16 q-tiles of one (h,b) on one XCD
  const int flatb = blockIdx.x + 16 * blockIdx.y + 128 * blockIdx.z;
  const int hb = (flatb % 8) + 8 * ((flatb / 8) / 16);
  const int qb = (flatb / 8) % 16;
  const int h = hb % 8, b = hb / 8;

  const int t  = threadIdx.x;
  const int l  = t & 63, ws = t >> 6;
  const int ln = l & 15, lg = l >> 4;

  __shared__ unsigned short Ph[4][16 * 64];
  __shared__ unsigned short Pl[4][16 * 64];

  const size_t qkbase = (size_t)b * 1024 * 1024;
  const int qrow = qb * 64 + ws * 16 + ln;
  const size_t qoff = qkbase + (size_t)qrow * 1024 + h * 64;

  bf16x8 q_h[2], q_l[2];
#pragma unroll
  for (int ks = 0; ks < 2; ++ks) {
    q_h[ks] = *(const bf16x8*)(qk_hi + qoff + ks * 32 + lg * 8);
    q_l[ks] = *(const bf16x8*)(qk_lo + qoff + ks * 32 + lg * 8);
  }

  float m_run[4], l_run[4];
  f32x4 acc_o[4];
#pragma unroll
  for (int r = 0; r < 4; ++r) { m_run[r] = -INFINITY; l_run[r] = 0.f; }
#pragma unroll
  for (int fd = 0; fd < 4; ++fd) acc_o[fd] = (f32x4){0.f, 0.f, 0.f, 0.f};

  const int kcol = 512 + h * 64;
  const size_t vbase = ((size_t)b * 512 + h * 64) * 1024;

  for (int mt = 0; mt < 16; ++mt) {
    const int mb = mt * 64;
    // ---- S = Q K^T (3-term split) ----
    f32x4 acc_s[4];
#pragma unroll
    for (int fn = 0; fn < 4; ++fn) acc_s[fn] = (f32x4){0.f, 0.f, 0.f, 0.f};
#pragma unroll
    for (int ks = 0; ks < 2; ++ks) {
#pragma unroll
      for (int fn = 0; fn < 4; ++fn) {
        const size_t koff = qkbase + (size_t)(mb + fn * 16 + ln) * 1024 + kcol + ks * 32 + lg * 8;
        const bf16x8 kh = *(const bf16x8*)(qk_hi + koff);
        const bf16x8 kl = *(const bf16x8*)(qk_lo + koff);
        acc_s[fn] = __builtin_amdgcn_mfma_f32_16x16x32_bf16(q_h[ks], kh, acc_s[fn], 0, 0, 0);
        acc_s[fn] = __builtin_amdgcn_mfma_f32_16x16x32_bf16(q_h[ks], kl, acc_s[fn], 0, 0, 0);
        acc_s[fn] = __builtin_amdgcn_mfma_f32_16x16x32_bf16(q_l[ks], kh, acc_s[fn], 0, 0, 0);
      }
    }
    // ---- online softmax (rows n = 4*lg + r are lane-local) ----
    float al[4];
#pragma unroll
    for (int r = 0; r < 4; ++r) {
      float s0 = acc_s[0][r] * SCALE, s1 = acc_s[1][r] * SCALE;
      float s2 = acc_s[2][r] * SCALE, s3 = acc_s[3][r] * SCALE;
      float tm = fmaxf(fmaxf(s0, s1), fmaxf(s2, s3));
#pragma unroll
      for (int msk = 8; msk >= 1; msk >>= 1) tm = fmaxf(tm, __shfl_xor(tm, msk));
      const float mn = fmaxf(m_run[r], tm);
      al[r] = __expf(m_run[r] - mn);
      m_run[r] = mn;
      const float p0 = __expf(s0 - mn), p1 = __expf(s1 - mn);
      const float p2 = __expf(s2 - mn), p3 = __expf(s3 - mn);
      float rs = p0 + p1 + p2 + p3;
#pragma unroll
      for (int msk = 8; msk >= 1; msk >>= 1) rs += __shfl_xor(rs, msk);
      l_run[r] = l_run[r] * al[r] + rs;
      const int n = 4 * lg + r;
      const int sw = (n >> 1) & 7;
      const float pv4[4] = {p0, p1, p2, p3};
#pragma unroll
      for (int fn = 0; fn < 4; ++fn) {
        const int m = fn * 16 + ln;
        const unsigned short hb = f2bf(pv4[fn]);
        const int idx = n * 64 + ((m >> 3) ^ sw) * 8 + (m & 7);
        Ph[ws][idx] = hb;
        Pl[ws][idx] = f2bf(pv4[fn] - bf2f(hb));
      }
    }
#pragma unroll
    for (int fd = 0; fd < 4; ++fd) {
      f32x4 a = acc_o[fd];
      a[0] *= al[0]; a[1] *= al[1]; a[2] *= al[2]; a[3] *= al[3];
      acc_o[fd] = a;
    }
    // ---- PV (3-term split); P A-frag rows n = ln ----
#pragma unroll
    for (int ks = 0; ks < 2; ++ks) {
      const int pc = ((ks * 4 + lg) ^ ((ln >> 1) & 7)) * 8;
      const bf16x8 pah = *(const bf16x8*)&Ph[ws][ln * 64 + pc];
      const bf16x8 pal = *(const bf16x8*)&Pl[ws][ln * 64 + pc];
#pragma unroll
      for (int fd = 0; fd < 4; ++fd) {
        const size_t voff = vbase + (size_t)(fd * 16 + ln) * 1024 + mb + ks * 32 + lg * 8;
        const bf16x8 vh = *(const bf16x8*)(vt_hi + voff);
        const bf16x8 vl = *(const bf16x8*)(vt_lo + voff);
        acc_o[fd] = __builtin_amdgcn_mfma_f32_16x16x32_bf16(pah, vh, acc_o[fd], 0, 0, 0);
        acc_o[fd] = __builtin_amdgcn_mfma_f32_16x16x32_bf16(pah, vl, acc_o[fd], 0, 0, 0);
        acc_o[fd] = __builtin_amdgcn_mfma_f32_16x16x32_bf16(pal, vh, acc_o[fd], 0, 0, 0);
      }
    }
  }
  // ---- epilogue: normalize, split-bf16 out [b][hw][512] ----
  float inv[4];
#pragma unroll
  for (int r = 0; r < 4; ++r) inv[r] = 1.f / l_run[r];
#pragma unroll
  for (int fd = 0; fd < 4; ++fd) {
#pragma unroll
    for (int r = 0; r < 4; ++r) {
      const int row = qb * 64 + ws * 16 + 4 * lg + r;
      const int col = h * 64 + fd * 16 + ln;
      const float v = acc_o[fd][r] * inv[r];
      const unsigned short hb = f2bf(v);
      const size_t off = ((size_t)b * 1024 + row) * 512 + col;
      att_hi[off] = hb;
      att_lo[off] = f2bf(v - bf2f(hb));
    }
  }
}

// ---------- proj GEMM (verified round-4 kernel, fp32 out + bias + residual) ----------
__global__ __launch_bounds__(256, 2) void gemm_bt_split(
    const unsigned short* __restrict__ Ah, const unsigned short* __restrict__ Al,
    const unsigned short* __restrict__ Bh0, const unsigned short* __restrict__ Bl0,
    const float* __restrict__ bias, const float* __restrict__ R0,
    float* __restrict__ C0, int M) {
  const int n0 = blockIdx.x * 128;
  const int m0 = blockIdx.y * 128;
  const int b  = blockIdx.z;
  const unsigned short* __restrict__ Bh = Bh0 + (size_t)b * HW * C_CH;
  const unsigned short* __restrict__ Bl = Bl0 + (size_t)b * HW * C_CH;
  float* __restrict__ Cp = C0 + (size_t)b * M * HW;
  const float* __restrict__ Rp = R0 ? (R0 + (size_t)b * M * HW) : nullptr;

  __shared__ unsigned short sAh[128 * 64], sAl[128 * 64], sBh[128 * 64], sBl[128 * 64];

  const int t  = threadIdx.x;
  const int l  = t & 63, w = t >> 6;
  const int wm = w >> 1, wn = w & 1;
  const int ln = l & 15, lg = l >> 4;

  f32x4 acc[4][4];
#pragma unroll
  for (int i = 0; i < 4; ++i)
#pragma unroll
    for (int j = 0; j < 4; ++j) acc[i][j] = (f32x4){0.f, 0.f, 0.f, 0.f};

  for (int k0 = 0; k0 < C_CH; k0 += 64) {
    __syncthreads();
#pragma unroll
    for (int rr = 0; rr < 4; ++rr) {
      const int flat = rr * 256 + t;
      const int row = flat >> 3, ch = flat & 7;
      const int dst = row * 64 + (ch ^ (row & 7)) * 8;
      const size_t asrc = (size_t)(m0 + row) * C_CH + k0 + ch * 8;
      const size_t bsrc = (size_t)(n0 + row) * C_CH + k0 + ch * 8;
      *(bf16x8*)&sAh[dst] = *(const bf16x8*)(Ah + asrc);
      *(bf16x8*)&sAl[dst] = *(const bf16x8*)(Al + asrc);
      *(bf16x8*)&sBh[dst] = *(const bf16x8*)(Bh + bsrc);
      *(bf16x8*)&sBl[dst] = *(const bf16x8*)(Bl + bsrc);
    }
    __syncthreads();
#pragma unroll
    for (int ks = 0; ks < 2; ++ks) {
      bf16x8 bhf[4], blf[4];
#pragma unroll
      for (int fn = 0; fn < 4; ++fn) {
        const int row = wn * 64 + fn * 16 + ln;
        const int off = row * 64 + ((ks * 4 + lg) ^ (row & 7)) * 8;
        bhf[fn] = *(const bf16x8*)&sBh[off];
        blf[fn] = *(const bf16x8*)&sBl[off];
      }
#pragma unroll
      for (int fm = 0; fm < 4; ++fm) {
        const int row = wm * 64 + fm * 16 + ln;
        const int off = row * 64 + ((ks * 4 + lg) ^ (row & 7)) * 8;
        const bf16x8 ahf = *(const bf16x8*)&sAh[off];
        const bf16x8 alf = *(const bf16x8*)&sAl[off];
#pragma unroll
        for (int fn = 0; fn < 4; ++fn) {
          acc[fm][fn] = __builtin_amdgcn_mfma_f32_16x16x32_bf16(ahf, bhf[fn], acc[fm][fn], 0, 0, 0);
          acc[fm][fn] = __builtin_amdgcn_mfma_f32_16x16x32_bf16(ahf, blf[fn], acc[fm][fn], 0, 0, 0);
          acc[fm][fn] = __builtin_amdgcn_mfma_f32_16x16x32_bf16(alf, bhf[fn], acc[fm][fn], 0, 0, 0);
        }
      }
    }
  }
#pragma unroll
  for (int fm = 0; fm < 4; ++fm) {
#pragma unroll
    for (int r = 0; r < 4; ++r) {
      const int row = m0 + wm * 64 + fm * 16 + lg * 4 + r;
      const float bi = bias[row];
#pragma unroll
      for (int fn = 0; fn < 4; ++fn) {
        const int col = n0 + wn * 64 + fn * 16 + ln;
        const size_t off = (size_t)row * HW + col;
        float vo = acc[fm][fn][r] + bi;
        if (Rp) vo += Rp[off];
        Cp[off] = vo;
      }
    }
  }
}

// ---------------- launch ----------------
extern "C" void kernel_launch(void* const* d_in, const int* in_sizes, int n_in,
                              void* d_out, int out_size, void* d_ws, size_t ws_size,
                              hipStream_t stream) {
  (void)in_sizes; (void)n_in; (void)out_size; (void)ws_size;
  const float* x     = (const float*)d_in[0];
  const float* gamma = (const float*)d_in[1];
  const float* beta  = (const float*)d_in[2];
  const float* w_qkv = (const float*)d_in[3];
  const float* b_qkv = (const float*)d_in[4];
  const float* w_out = (const float*)d_in[5];
  const float* b_out = (const float*)d_in[6];
  float* out = (float*)d_out;

  // ws (128 MiB), liveness-planned:
  // [0,16M)=xnt_hi -> vt_hi ; [16M,32M)=xnt_lo -> vt_lo
  // [32M,64M)=qk_hi (wo hi/lo reuse after attn) ; [64M,96M)=qk_lo
  // [96M,112M)=vb_hi -> att_hi ; [112M,128M)=vb_lo -> att_lo
  char* wsb = (char*)d_ws;
  unsigned short* xnt_hi = (unsigned short*)wsb;
  unsigned short* xnt_lo = (unsigned short*)(wsb + (size_t)16 * 1024 * 1024);
  unsigned short* qk_hi  = (unsigned short*)(wsb + (size_t)32 * 1024 * 1024);
  unsigned short* qk_lo  = (unsigned short*)(wsb + (size_t)64 * 1024 * 1024);
  unsigned short* vb_hi  = (unsigned short*)(wsb + (size_t)96 * 1024 * 1024);
  unsigned short* vb_lo  = (unsigned short*)(wsb + (size_t)112 * 1024 * 1024);
  unsigned short* vt_hi  = xnt_hi;
  unsigned short* vt_lo  = xnt_lo;
  unsigned short* att_hi = vb_hi;
  unsigned short* att_lo = vb_lo;
  unsigned short* wo_hi  = qk_hi;            // qk dead after attn
  unsigned short* wo_lo  = qk_hi + 512 * 512;
  unsigned short* wq_hi  = (unsigned short*)d_out;   // d_out dead until proj
  unsigned short* wq_lo  = wq_hi + (size_t)1536 * 512;

  wconv<<<dim3(384), 256, 0, stream>>>(w_qkv, wq_hi, wq_lo, 98304);
  gn_t_kernel<<<dim3(GROUPS, 16), 256, 0, stream>>>(x, gamma, beta, xnt_hi, xnt_lo);
  gemm_xw<<<dim3(12, 8, 16), 256, 0, stream>>>(xnt_hi, xnt_lo, wq_hi, wq_lo, b_qkv,
                                               qk_hi, qk_lo, vb_hi, vb_lo);
  vt_kernel<<<dim3(16, 8, 16), 256, 0, stream>>>(vb_hi, vb_lo, vt_hi, vt_lo);
  attn_mfma<<<dim3(16, 8, 16), 256, 0, stream>>>(qk_hi, qk_lo, vt_hi, vt_lo, att_hi, att_lo);
  wconv<<<dim3(128), 256, 0, stream>>>(w_out, wo_hi, wo_lo, 32768);
  gemm_bt_split<<<dim3(8, 4, 16), 256, 0, stream>>>(wo_hi, wo_lo, att_hi, att_lo,
                                                    b_out, x, out, C_CH);
}